// Round 10
// baseline (298.673 us; speedup 1.0000x reference)
//
#include <hip/hip_runtime.h>
#include <math.h>

#define D   1024
#define H   16
#define HD  64
#define SEQ 2048
#define LL  8
#define SCALE 0.125f

typedef __attribute__((ext_vector_type(8))) __bf16 bf16x8;
typedef __attribute__((ext_vector_type(4))) float floatx4;
typedef __attribute__((ext_vector_type(8))) unsigned short ushort8;
typedef __attribute__((ext_vector_type(4))) unsigned int uintx4;

__device__ inline unsigned short f32_to_bf16(float f) {
    unsigned int u = __builtin_bit_cast(unsigned int, f);
    u += 0x7FFF + ((u >> 16) & 1);   // round-to-nearest-even
    return (unsigned short)(u >> 16);
}
__device__ inline float bf2f(unsigned short u) {
    unsigned int x = (unsigned int)u << 16;
    return __builtin_bit_cast(float, x);
}
__device__ inline unsigned int cvt_pk_bf16(float lo, float hi) {
    unsigned int r;
    asm("v_cvt_pk_bf16_f32 %0, %1, %2" : "=v"(r) : "v"(lo), "v"(hi));
    return r;
}
__device__ inline void load_lds16(const void* g, void* l) {
    __builtin_amdgcn_global_load_lds(
        (__attribute__((address_space(1))) void*)g,
        (__attribute__((address_space(3))) void*)l, 16, 0, 0);
}

// XCD-aware swizzle: contiguous grid chunk per XCD -> A-panel L2 reuse.
__device__ inline void xcd_swizzle(int& bx, int& by) {
    const int gx   = gridDim.x;
    const int lin  = blockIdx.y * gx + blockIdx.x;
    const int nblk = gx * gridDim.y;
    const int virt = (lin & 7) * (nblk >> 3) + (lin >> 3);
    bx = virt % gx;
    by = virt / gx;
}

// ---------------------------------------------------------------------------
// prep_ln: LN(reproject(pv)) -> ri_bf. Wave handles a ROW-QUAD (l, s0..s0+3):
// per h-plane one 4KB fully-contiguous load; 16 independent loads/wave.
// Split from the convert kernel for separable counters.
// ---------------------------------------------------------------------------
#define LN_BLK  1024          // 4 waves/block x 1 row-quad/wave = 4096 quads

__global__ __launch_bounds__(256) void prep_ln_kernel(
    const float* __restrict__ pv, unsigned short* __restrict__ ri)
{
    const int b = blockIdx.x;
    const int t = threadIdx.x;
    const int w = t >> 6, lane = t & 63;
    const int qi = b * 4 + w;            // 0..4095 row-quads
    const int l  = qi & 7;
    const int s0 = (qi >> 3) * 4;
    const int sl = lane >> 4;            // s_local 0..3
    const int e  = (lane & 15) * 4;
    const float* base = pv + (size_t)l * (H * SEQ * HD) + (size_t)s0 * HD;
    float4 v[16];
#pragma unroll
    for (int h = 0; h < 16; h++)
        v[h] = *(const float4*)(base + (size_t)h * (SEQ * HD) + lane * 4);
    float sum = 0.f, sq = 0.f;
#pragma unroll
    for (int h = 0; h < 16; h++) {
        sum += (v[h].x + v[h].y) + (v[h].z + v[h].w);
        sq  += (v[h].x * v[h].x + v[h].y * v[h].y)
             + (v[h].z * v[h].z + v[h].w * v[h].w);
    }
#pragma unroll
    for (int off = 1; off < 16; off <<= 1) {
        sum += __shfl_xor(sum, off);
        sq  += __shfl_xor(sq, off);
    }
    const float mean = sum * (1.f / 1024.f);
    const float var  = sq * (1.f / 1024.f) - mean * mean;
    const float rstd = rsqrtf(var + 1e-5f);
    const int r = (s0 + sl) * 8 + l;
#pragma unroll
    for (int h = 0; h < 16; h++) {
        ushort4 o;
        o.x = f32_to_bf16((v[h].x - mean) * rstd);
        o.y = f32_to_bf16((v[h].y - mean) * rstd);
        o.z = f32_to_bf16((v[h].z - mean) * rstd);
        o.w = f32_to_bf16((v[h].w - mean) * rstd);
        *(ushort4*)(ri + (size_t)r * D + h * 64 + e) = o;
    }
}

// ---------------------------------------------------------------------------
// prep_cvt: f32->bf16 of x, Wqkv|Wcol (->W4), Wout (4 quads/thread)
//           | bias concat b4 = [bqkv, bcol]
// ---------------------------------------------------------------------------
#define NQ_X    524288
#define NQ_WQKV 786432
#define NQ_WC   262144
#define NQ_WO   262144
#define CVT_BLK 1792          // 1835008 quads / (256 thr * 4 quads)

__global__ __launch_bounds__(256) void prep_cvt_kernel(
    const float* __restrict__ x, const float* __restrict__ Wqkv,
    const float* __restrict__ Wcol, const float* __restrict__ Wout,
    const float* __restrict__ bqkv, const float* __restrict__ bcol,
    unsigned short* __restrict__ xb, unsigned short* __restrict__ W4b,
    unsigned short* __restrict__ Woutb, float* __restrict__ b4)
{
    const int b = blockIdx.x;
    const int t = threadIdx.x;
    if (b < CVT_BLK) {
        const int base = b * 1024;
#pragma unroll
        for (int j = 0; j < 4; j++) {
            const int i = base + j * 256 + t;
            const float* src; unsigned short* dst; int soff, doff;
            if (i < NQ_X)                        { src = x;    dst = xb;    soff = i;                          doff = soff; }
            else if (i < NQ_X + NQ_WQKV)         { src = Wqkv; dst = W4b;   soff = i - NQ_X;                   doff = soff; }
            else if (i < NQ_X + NQ_WQKV + NQ_WC) { src = Wcol; dst = W4b;   soff = i - NQ_X - NQ_WQKV;         doff = i - NQ_X; }
            else                                 { src = Wout; dst = Woutb; soff = i - NQ_X - NQ_WQKV - NQ_WC; doff = soff; }
            float4 v = ((const float4*)src)[soff];
            ushort4 o;
            o.x = f32_to_bf16(v.x); o.y = f32_to_bf16(v.y);
            o.z = f32_to_bf16(v.z); o.w = f32_to_bf16(v.w);
            ((ushort4*)dst)[doff] = o;
        }
    } else {
        // bias concat: 1024 float4 quads, first 768 from bqkv, rest from bcol
        const int q = (b - CVT_BLK) * 256 + t;
        float4 v = (q < 768) ? ((const float4*)bqkv)[q] : ((const float4*)bcol)[q - 768];
        ((float4*)b4)[q] = v;
    }
}

// ---------------------------------------------------------------------------
// wkt: WkT[h][c][e] = Wqkv[1024 + h*64 + e][c]  (bf16). Grid 256 = 16h x 16ct.
// ---------------------------------------------------------------------------
__global__ __launch_bounds__(256) void wkt_kernel(
    const float* __restrict__ Wqkv, unsigned short* __restrict__ WkT)
{
    const int h = blockIdx.x >> 4, ct = blockIdx.x & 15;
    const int c0 = ct * 64;
    const int t = threadIdx.x;
    __shared__ float tile[64][68];
    {
        const int e  = t >> 2;            // 0..63
        const int c4 = (t & 3) * 16;      // 0,16,32,48
        const float* src = Wqkv + (size_t)(D + h * HD + e) * D + c0 + c4;
#pragma unroll
        for (int j = 0; j < 4; j++) {
            float4 v = ((const float4*)src)[j];
            *(float4*)&tile[e][c4 + j * 4] = v;
        }
    }
    __syncthreads();
    {
        const int c  = t >> 2;            // local col 0..63
        const int e0 = (t & 3) * 16;      // 0,16,32,48
        ushort8 o0, o1;
#pragma unroll
        for (int j = 0; j < 8; j++) o0[j] = f32_to_bf16(tile[e0 + j][c]);
#pragma unroll
        for (int j = 0; j < 8; j++) o1[j] = f32_to_bf16(tile[e0 + 8 + j][c]);
        unsigned short* dst = WkT + (size_t)h * (D * HD) + (size_t)(c0 + c) * HD + e0;
        *(ushort8*)dst       = o0;
        *(ushort8*)(dst + 8) = o1;
    }
}

// ---------------------------------------------------------------------------
// vtr: VT[h][e][key] = V[key][h*64+e]  (global transpose of the V quarter of
// qkv4). Grid 128 = 16h x 8 key-chunks of 256. LDS-tiled, coalesced both ways.
// ---------------------------------------------------------------------------
__global__ __launch_bounds__(256) void vtr_kernel(
    const unsigned short* __restrict__ qkv4, unsigned short* __restrict__ VT)
{
    const int h = blockIdx.x & 15, kt = blockIdx.x >> 4;
    const int t = threadIdx.x;
    __shared__ unsigned short Vt[64][264];
    const int pr = t & 31, eg = t >> 5;   // key-pair 0..31, e-octet 0..7
#pragma unroll
    for (int sub = 0; sub < 4; sub++) {
        const int j0 = kt * 256 + sub * 64;
        const unsigned short* v0 = qkv4 + (size_t)(j0 + 2 * pr) * 4096 + 2 * D + h * HD + eg * 8;
        ushort8 va = *(const ushort8*)v0;
        ushort8 vb = *(const ushort8*)(v0 + 4096);
#pragma unroll
        for (int j = 0; j < 8; j++) {
            unsigned int pk = (unsigned int)va[j] | ((unsigned int)vb[j] << 16);
            *(unsigned int*)&Vt[eg * 8 + j][sub * 64 + 2 * pr] = pk;
        }
    }
    __syncthreads();
#pragma unroll
    for (int it = 0; it < 8; it++) {
        const int idx = it * 256 + t;
        const int e = idx >> 5, ch = idx & 31;
        ushort8 v = *(const ushort8*)&Vt[e][ch * 8];
        *(ushort8*)(VT + (size_t)h * (HD * SEQ) + (size_t)e * SEQ + kt * 256 + ch * 8) = v;
    }
}

// ---------------------------------------------------------------------------
// bf16 MFMA GEMM: C[M,N] = A[M,K] @ W[N,K]^T (+ bias[N]). CT = float or ushort.
// BMx128 tile (BM = 128 or 64), BK=32, 4 waves. XCD-swizzled.
// ---------------------------------------------------------------------------
template <typename CT, bool HAS_BIAS, int BM>
__global__ __launch_bounds__(256) void gemm_bf16_kernel(
    const unsigned short* __restrict__ A, const unsigned short* __restrict__ W,
    const float* __restrict__ bias, CT* __restrict__ C,
    int K, int N, int lda, int ldw, int ldc,
    size_t zsA, size_t zsW, size_t zsC)
{
    A += (size_t)blockIdx.z * zsA;
    W += (size_t)blockIdx.z * zsW;
    C += (size_t)blockIdx.z * zsC;

    constexpr int MR = BM / 32;              // acc m-fragments per wave
    __shared__ unsigned short As[BM * 32];
    __shared__ unsigned short Ws[128 * 32];
    const int t    = threadIdx.x;
    const int wave = t >> 6, lane = t & 63;
    const int wm   = wave >> 1, wn = wave & 1;
    int bx, by;
    xcd_swizzle(bx, by);
    const int m0 = by * BM, n0 = bx * 128;

    floatx4 acc[MR][4];
#pragma unroll
    for (int i = 0; i < MR; i++)
#pragma unroll
        for (int j = 0; j < 4; j++) acc[i][j] = (floatx4)0.f;

    const int lrow = lane >> 2;
    const int lcol = (lane & 3) * 8;
    const int arows = (BM == 128) ? wave * 32 : wave * 16;
    const unsigned short* Ag = A + (size_t)(m0 + arows + lrow) * lda + lcol;
    const unsigned short* Wg = W + (size_t)(n0 + wave * 32 + lrow) * ldw + lcol;
    unsigned short* Asw = &As[arows * 32];
    unsigned short* Wsw = &Ws[wave * 32 * 32];
    const size_t rowskipA = (size_t)16 * lda;
    const size_t rowskipW = (size_t)16 * ldw;

    const int arow  = lane & 15;
    const int aquad = (lane >> 4) * 8;

    for (int k0 = 0; k0 < K; k0 += 32) {
        load_lds16(Ag + k0, Asw);
        if constexpr (BM == 128)
            load_lds16(Ag + k0 + rowskipA, Asw + 16 * 32);
        load_lds16(Wg + k0,             Wsw);
        load_lds16(Wg + k0 + rowskipW,  Wsw + 16 * 32);
        __syncthreads();

        bf16x8 af[MR], wf[4];
#pragma unroll
        for (int mi = 0; mi < MR; mi++)
            af[mi] = *(const bf16x8*)&As[(wm * (BM / 2) + mi * 16 + arow) * 32 + aquad];
#pragma unroll
        for (int ni = 0; ni < 4; ni++)
            wf[ni] = *(const bf16x8*)&Ws[(wn * 64 + ni * 16 + arow) * 32 + aquad];
#pragma unroll
        for (int mi = 0; mi < MR; mi++)
#pragma unroll
            for (int ni = 0; ni < 4; ni++)
                acc[mi][ni] = __builtin_amdgcn_mfma_f32_16x16x32_bf16(
                    af[mi], wf[ni], acc[mi][ni], 0, 0, 0);
        __syncthreads();
    }

    const int crow = (lane >> 4) * 4, ccol = lane & 15;
#pragma unroll
    for (int mi = 0; mi < MR; mi++) {
#pragma unroll
        for (int ni = 0; ni < 4; ni++) {
            const int gm = m0 + wm * (BM / 2) + mi * 16 + crow;
            const int gn = n0 + wn * 64 + ni * 16 + ccol;
            float bb = 0.f;
            if constexpr (HAS_BIAS) bb = bias[gn];
#pragma unroll
            for (int r = 0; r < 4; r++) {
                float v = acc[mi][ni][r] + bb;
                if constexpr (sizeof(CT) == 2)
                    C[(size_t)(gm + r) * ldc + gn] = (CT)f32_to_bf16(v);
                else
                    C[(size_t)(gm + r) * ldc + gn] = v;
            }
        }
    }
}

// ---------------------------------------------------------------------------
// memsc (MFMA, zero-staging): scores[s,h,l] = (U[s,h,:].ri[s,l,:] + qb)*SCALE
// U layout [s][h][d]. Fragments read DIRECTLY from global (each byte consumed
// exactly once -> LDS staging was pure overhead). Only a 4KB reduce buffer.
// ---------------------------------------------------------------------------
__global__ __launch_bounds__(256) void memsc_kernel(
    const unsigned short* __restrict__ U, const unsigned short* __restrict__ ri,
    const unsigned short* __restrict__ qkv4, const float* __restrict__ bqkv,
    float* __restrict__ scores)
{
    const int s = blockIdx.x;
    const int t = threadIdx.x;
    const int w = t >> 6, lane = t & 63;
    const int lrow = lane & 15;
    const int lkq  = (lane >> 4) * 8;

    __shared__ float red[4][16][16];
    __shared__ float qbS[H];

    // qb[h] = qcol[s,h,:] . bk[h,:]
    {
        const int h = t >> 4, sub = t & 15;
        const unsigned short* qc = qkv4 + (size_t)s * 4096 + 3 * D + h * HD + sub * 4;
        const float* bk = bqkv + D + h * HD + sub * 4;
        float acc = 0.f;
#pragma unroll
        for (int j = 0; j < 4; j++) acc += bf2f(qc[j]) * bk[j];
#pragma unroll
        for (int off = 1; off < 16; off <<= 1) acc += __shfl_xor(acc, off);
        if (sub == 0) qbS[h] = acc;
    }

    // each wave: 8 MFMA k-steps over its 256-wide K-quarter, frags from global
    const unsigned short* Up = U + (size_t)s * (H * D) + lrow * D;     // h = lrow
    const unsigned short* rp = ri + (size_t)s * (LL * D) + lrow * D;   // l = lrow
    floatx4 acc = (floatx4)0.f;
    const int kbase = w * 256;
#pragma unroll
    for (int step = 0; step < 8; step++) {
        const int k0 = kbase + step * 32 + lkq;
        bf16x8 af = *(const bf16x8*)(Up + k0);
        bf16x8 bf = {};
        if (lrow < 8) bf = *(const bf16x8*)(rp + k0);
        acc = __builtin_amdgcn_mfma_f32_16x16x32_bf16(af, bf, acc, 0, 0, 0);
    }

    {
        const int crow = (lane >> 4) * 4, ccol = lane & 15;
#pragma unroll
        for (int r = 0; r < 4; r++) red[w][crow + r][ccol] = acc[r];
    }
    __syncthreads();

    if (t < H * LL) {
        const int h = t >> 3, l = t & 7;
        float v = red[0][h][l] + red[1][h][l] + red[2][h][l] + red[3][h][l];
        scores[((size_t)s * H + h) * LL + l] = (v + qbS[h]) * SCALE;
    }
}

// ---------------------------------------------------------------------------
// Split-K MFMA flash attention, 4-way split, LPT order. Swapped-QK^T (T12):
// S^T = mfma(K,Q) so each lane owns q = lane&15 -> softmax reduce = 2 shfls,
// m/l are per-lane scalars. P->bf16 via v_cvt_pk_bf16_f32 + 2-round lane
// butterfly (xor32 then xor16) assembles PV B-frags fully in registers -- no
// P LDS buffer. PV = mfma(V^T, P) -> O^T; epilogue = 4x float4 stores.
// Double-buffered K/V staging, ONE barrier per tile (proof in R4 notes).
// ---------------------------------------------------------------------------
__global__ __launch_bounds__(256, 4) void attn_split_kernel(
    const unsigned short* __restrict__ qkv4, const unsigned short* __restrict__ VT,
    float* __restrict__ Opart, float2* __restrict__ mlpart)
{
    const int t    = threadIdx.x;
    const int w    = t >> 6, lane = t & 63;
    const int lrow = lane & 15;           // q-row / e-row / key-col of fragments
    const int lk   = (lane >> 4) * 8;
    const int qd   = lane >> 4;           // lane quarter 0..3
    const int hi2  = qd >> 1, lo2 = qd & 1;
    const int lin  = blockIdx.x;
    const int hsp  = lin & 63, g = lin >> 6;
    const int s    = hsp >> 4, h = hsp & 15;
    const int qt   = 31 - g;              // LPT: longest first
    const int q0   = qt * 64;
    const int n    = qt + 1;
    const int lo   = (s * n) >> 2, hi = ((s + 1) * n) >> 2;
    const int part = (h * 32 + qt) * 4 + s;

    __shared__ unsigned short Ks[2][64 * 72];   // [key][e], dbuf
    __shared__ unsigned short Vs[2][64 * 72];   // [e][key], dbuf

    // Q fragments in registers, pre-scaled by 1/8 (exact pow-2 in bf16)
    bf16x8 qreg[2];
#pragma unroll
    for (int kst = 0; kst < 2; kst++) {
        ushort8 qu = *(const ushort8*)(qkv4 + (size_t)(q0 + w * 16 + lrow) * 4096
                                       + h * HD + kst * 32 + lk);
        ushort8 qs;
#pragma unroll
        for (int j = 0; j < 8; j++) qs[j] = f32_to_bf16(bf2f(qu[j]) * SCALE);
        qreg[kst] = __builtin_bit_cast(bf16x8, qs);
    }
    const int qg = q0 + w * 16 + lrow;    // this lane's global q row

    // staging map: thread covers rows {srow, srow+32}, 16B at column scol
    const int srow = t >> 3;            // 0..31
    const int scol = (t & 7) * 8;       // 0..56
    const unsigned short* Kg = qkv4 + D + h * HD;              // + key*4096
    const unsigned short* Vg = VT + (size_t)h * (HD * SEQ);    // + e*SEQ + key

    bf16x8 kr0, kr1, vr0, vr1;
    float m_i = -1e30f, l_i = 0.f;
    floatx4 Oacc[4];
#pragma unroll
    for (int et = 0; et < 4; et++) Oacc[et] = (floatx4)0.f;

    // prologue: load tile 'lo' into regs
    if (lo < hi) {
        const int j0 = lo * 64;
        kr0 = *(const bf16x8*)(Kg + (size_t)(j0 + srow) * 4096 + scol);
        kr1 = *(const bf16x8*)(Kg + (size_t)(j0 + 32 + srow) * 4096 + scol);
        vr0 = *(const bf16x8*)(Vg + (size_t)srow * SEQ + j0 + scol);
        vr1 = *(const bf16x8*)(Vg + (size_t)(srow + 32) * SEQ + j0 + scol);
    }

    int cur = 0;
    for (int jt = lo; jt < hi; jt++) {
        const int j0 = jt * 64;
        // write current tile's regs into buf[cur]
        *(bf16x8*)&Ks[cur][srow * 72 + scol]        = kr0;
        *(bf16x8*)&Ks[cur][(srow + 32) * 72 + scol] = kr1;
        *(bf16x8*)&Vs[cur][srow * 72 + scol]        = vr0;
        *(bf16x8*)&Vs[cur][(srow + 32) * 72 + scol] = vr1;
        // issue next tile's loads (hide under this tile's compute)
        if (jt + 1 < hi) {
            const int j0n = (jt + 1) * 64;
            kr0 = *(const bf16x8*)(Kg + (size_t)(j0n + srow) * 4096 + scol);
            kr1 = *(const bf16x8*)(Kg + (size_t)(j0n + 32 + srow) * 4096 + scol);
            vr0 = *(const bf16x8*)(Vg + (size_t)srow * SEQ + j0n + scol);
            vr1 = *(const bf16x8*)(Vg + (size_t)(srow + 32) * SEQ + j0n + scol);
        }
        __syncthreads();                 // staging of buf[cur] visible

        // S^T = K Q^T : lane holds q = lane&15, keys nt*16 + qd*4 + r
        floatx4 S[4];
#pragma unroll
        for (int nt = 0; nt < 4; nt++) S[nt] = (floatx4)0.f;
        __builtin_amdgcn_s_setprio(1);
#pragma unroll
        for (int kst = 0; kst < 2; kst++) {
#pragma unroll
            for (int nt = 0; nt < 4; nt++) {
                bf16x8 bk = *(const bf16x8*)&Ks[cur][(nt * 16 + lrow) * 72 + kst * 32 + lk];
                S[nt] = __builtin_amdgcn_mfma_f32_16x16x32_bf16(bk, qreg[kst], S[nt], 0, 0, 0);
            }
        }
        __builtin_amdgcn_s_setprio(0);

        const bool diag = (jt == qt);
        if (diag) {
#pragma unroll
            for (int nt = 0; nt < 4; nt++)
#pragma unroll
                for (int r = 0; r < 4; r++)
                    if (j0 + nt * 16 + qd * 4 + r > qg) S[nt][r] = -1e30f;
        }
        float mx = -1e30f;
#pragma unroll
        for (int nt = 0; nt < 4; nt++)
            mx = fmaxf(mx, fmaxf(fmaxf(S[nt][0], S[nt][1]), fmaxf(S[nt][2], S[nt][3])));
        mx = fmaxf(mx, __shfl_xor(mx, 16));
        mx = fmaxf(mx, __shfl_xor(mx, 32));
        const bool keep = !diag && __all(mx <= m_i + 8.f);
        if (!keep) {
            const float newm = fmaxf(m_i, mx);
            const float a = __expf(m_i - newm);
            m_i = newm;
            l_i *= a;
#pragma unroll
            for (int et = 0; et < 4; et++) Oacc[et] *= a;
        }

        // P = exp(S - m); pack to bf16 pairs per tile (up[t][pair])
        float ps = 0.f;
        unsigned int up[4][2];
#pragma unroll
        for (int nt = 0; nt < 4; nt++) {
            float p0 = __expf(S[nt][0] - m_i);
            float p1 = __expf(S[nt][1] - m_i);
            float p2 = __expf(S[nt][2] - m_i);
            float p3 = __expf(S[nt][3] - m_i);
            ps += (p0 + p1) + (p2 + p3);
            up[nt][0] = cvt_pk_bf16(p0, p1);
            up[nt][1] = cvt_pk_bf16(p2, p3);
        }
        ps += __shfl_xor(ps, 16);
        ps += __shfl_xor(ps, 32);
        l_i += ps;

        // --- 2-round butterfly: redistribute P^T into PV B-fragments ---
        // Round 1 (xor32): send tiles with (t&1) != hi2.
        unsigned int s0 = hi2 ? up[0][0] : up[1][0];
        unsigned int s1 = hi2 ? up[0][1] : up[1][1];
        unsigned int s2 = hi2 ? up[2][0] : up[3][0];
        unsigned int s3 = hi2 ? up[2][1] : up[3][1];
        s0 = __shfl_xor(s0, 32); s1 = __shfl_xor(s1, 32);
        s2 = __shfl_xor(s2, 32); s3 = __shfl_xor(s3, 32);
        const unsigned int ownA0 = hi2 ? up[1][0] : up[0][0];   // tile tA = hi2
        const unsigned int ownA1 = hi2 ? up[1][1] : up[0][1];
        const unsigned int ownB0 = hi2 ? up[3][0] : up[2][0];   // tile tB = hi2+2
        const unsigned int ownB1 = hi2 ? up[3][1] : up[2][1];
        // Round 2 (xor16): keep source with s>>1 == lo2 (own iff hi2==lo2).
        const bool keepOwn = (hi2 == lo2);
        unsigned int eA0 = keepOwn ? s0 : ownA0;
        unsigned int eA1 = keepOwn ? s1 : ownA1;
        unsigned int eB0 = keepOwn ? s2 : ownB0;
        unsigned int eB1 = keepOwn ? s3 : ownB1;
        eA0 = __shfl_xor(eA0, 16); eA1 = __shfl_xor(eA1, 16);
        eB0 = __shfl_xor(eB0, 16); eB1 = __shfl_xor(eB1, 16);
        const unsigned int kA0 = keepOwn ? ownA0 : s0;
        const unsigned int kA1 = keepOwn ? ownA1 : s1;
        const unsigned int kB0 = keepOwn ? ownB0 : s2;
        const unsigned int kB1 = keepOwn ? ownB1 : s3;
        // final order: [sLo.p0, sLo.p1, sHi.p0, sHi.p1]; kept has s&1==lo2
        uintx4 fA = { lo2 ? eA0 : kA0, lo2 ? eA1 : kA1,
                      lo2 ? kA0 : eA0, lo2 ? kA1 : eA1 };
        uintx4 fB = { lo2 ? eB0 : kB0, lo2 ? eB1 : kB1,
                      lo2 ? kB0 : eB0, lo2 ? kB1 : eB1 };
        bf16x8 apA = __builtin_bit_cast(bf16x8, fA);   // kst=0 keys
        bf16x8 apB = __builtin_bit_cast(bf16x8, fB);   // kst=1 keys

        // O^T += V^T P : mfma(V^T_frag, P_frag) -> D[m=e][n=q]
        __builtin_amdgcn_s_setprio(1);
#pragma unroll
        for (int et = 0; et < 4; et++) {
            bf16x8 bv = *(const bf16x8*)&Vs[cur][(et * 16 + lrow) * 72 + lk];
            Oacc[et] = __builtin_amdgcn_mfma_f32_16x16x32_bf16(bv, apA, Oacc[et], 0, 0, 0);
        }
#pragma unroll
        for (int et = 0; et < 4; et++) {
            bf16x8 bv = *(const bf16x8*)&Vs[cur][(et * 16 + lrow) * 72 + 32 + lk];
            Oacc[et] = __builtin_amdgcn_mfma_f32_16x16x32_bf16(bv, apB, Oacc[et], 0, 0, 0);
        }
        __builtin_amdgcn_s_setprio(0);
        cur ^= 1;
    }

    // write partials: q = w*16+lrow, e = et*16 + qd*4 + r  -> float4 stores
#pragma unroll
    for (int et = 0; et < 4; et++) {
        float4 o = make_float4(Oacc[et][0], Oacc[et][1], Oacc[et][2], Oacc[et][3]);
        *(float4*)&Opart[((size_t)part * 64 + w * 16 + lrow) * 64 + et * 16 + qd * 4] = o;
    }
    if (qd == 0)
        mlpart[(size_t)part * 64 + w * 16 + lrow] = make_float2(m_i, l_i);
}

// ---------------------------------------------------------------------------
// merge: combine the four key-split partials per (h, qt) AND the 8 memory-key
// scores in one exact softmax; normalize. Writes token context (f32), final
// normalized mem weights mwf, and Pmem[s,h] = sum_l mwf.
// ---------------------------------------------------------------------------
__global__ __launch_bounds__(256) void attn_merge_kernel(
    const float* __restrict__ Opart, const float2* __restrict__ mlpart,
    const float* __restrict__ scores,
    float* __restrict__ tok, float* __restrict__ mwf, float* __restrict__ Pmem)
{
    const int blk = blockIdx.x;            // h*32 + qt
    const int h = blk >> 5, qt = blk & 31;
    const int q0 = qt * 64;
    const int t = threadIdx.x, tx = t & 15, ty = t >> 4;
    const size_t pb = (size_t)blk * 4;
#pragma unroll
    for (int i = 0; i < 4; i++) {
        const int qi = ty * 4 + i, qg = q0 + qi;
        float2 ml[4];
#pragma unroll
        for (int ps = 0; ps < 4; ps++) ml[ps] = mlpart[(pb + ps) * 64 + qi];
        const float* msp = scores + ((size_t)qg * H + h) * LL;
        float ms[LL];
#pragma unroll
        for (int l = 0; l < LL; l++) ms[l] = msp[l];
        float M = ml[0].x;
#pragma unroll
        for (int ps = 1; ps < 4; ps++) M = fmaxf(M, ml[ps].x);
#pragma unroll
        for (int l = 0; l < LL; l++) M = fmaxf(M, ms[l]);
        float f[4], L = 0.f;
#pragma unroll
        for (int ps = 0; ps < 4; ps++) { f[ps] = __expf(ml[ps].x - M); L += ml[ps].y * f[ps]; }
        float pm[LL];
#pragma unroll
        for (int l = 0; l < LL; l++) { pm[l] = __expf(ms[l] - M); L += pm[l]; }
        const float rl = 1.f / L;
        float4 o = make_float4(0.f, 0.f, 0.f, 0.f);
#pragma unroll
        for (int ps = 0; ps < 4; ps++) {
            const float fs = f[ps] * rl;
            float4 op = *(const float4*)&Opart[((pb + ps) * 64 + qi) * 64 + tx * 4];
            o.x += op.x * fs; o.y += op.y * fs; o.z += op.z * fs; o.w += op.w * fs;
        }
        *(float4*)&tok[(size_t)qg * D + h * HD + tx * 4] = o;
        if (tx == 0) {
            float* mw = mwf + ((size_t)qg * H + h) * LL;
            float psum = 0.f;
#pragma unroll
            for (int l = 0; l < LL; l++) { float v = pm[l] * rl; mw[l] = v; psum += v; }
            Pmem[(size_t)qg * H + h] = psum;
        }
    }
}

// ---------------------------------------------------------------------------
// rbar[h,s,:] = sum_l mwf[s,h,l] * ri[s*8+l,:]  (bf16 out). grid = 2048 (s).
// Zero-staging: ri values loaded once into registers (8 ushort4 -> 32 f32),
// reused across all 16 h; only mwf (512 B) goes through LDS.
// ---------------------------------------------------------------------------
__global__ __launch_bounds__(256) void rbar_kernel(
    const float* __restrict__ mwf, const unsigned short* __restrict__ ri,
    unsigned short* __restrict__ rbar)
{
    const int s = blockIdx.x, t = threadIdx.x;
    __shared__ float wS[H * LL];
    if (t < H * LL) wS[t] = mwf[(size_t)s * (H * LL) + t];
    const unsigned short* rp = ri + (size_t)s * (LL * D) + t * 4;
    float rv[LL][4];
#pragma unroll
    for (int l = 0; l < LL; l++) {
        ushort4 rr = *(const ushort4*)(rp + l * D);
        rv[l][0] = bf2f(rr.x); rv[l][1] = bf2f(rr.y);
        rv[l][2] = bf2f(rr.z); rv[l][3] = bf2f(rr.w);
    }
    __syncthreads();
    const int c4 = t * 4;
#pragma unroll
    for (int hh = 0; hh < H; hh++) {
        float v0 = 0.f, v1 = 0.f, v2 = 0.f, v3 = 0.f;
#pragma unroll
        for (int l = 0; l < LL; l++) {
            const float wv = wS[hh * LL + l];
            v0 += wv * rv[l][0]; v1 += wv * rv[l][1];
            v2 += wv * rv[l][2]; v3 += wv * rv[l][3];
        }
        ushort4 o;
        o.x = f32_to_bf16(v0); o.y = f32_to_bf16(v1);
        o.z = f32_to_bf16(v2); o.w = f32_to_bf16(v3);
        *(ushort4*)(rbar + ((size_t)hh * SEQ + s) * D + c4) = o;
    }
}

// ---------------------------------------------------------------------------
// ctx GEMM: ctx[s, h*64+e] = bf16( rbar[h,s,:] . Wv[h*64+e,:]
//                                  + bv[h*64+e]*Pmem[s,h] + tok[s,h*64+e] )
// 128(M)x64(N) tile, BK=32, 4 waves (wave = m-subtile). grid = (16 mt, 16 h).
// ---------------------------------------------------------------------------
__global__ __launch_bounds__(256) void gemm_ctx_kernel(
    const unsigned short* __restrict__ rbar, const unsigned short* __restrict__ W4,
    const float* __restrict__ bqkv, const float* __restrict__ Pmem,
    const float* __restrict__ tok, unsigned short* __restrict__ ctx)
{
    const int mt = blockIdx.x;      // 0..15
    const int h  = blockIdx.y;      // 0..15
    const unsigned short* A  = rbar + (size_t)h * SEQ * D + (size_t)mt * 128 * D;
    const unsigned short* Wv = W4 + (size_t)(2 * D + h * HD) * D;   // 64 rows x 1024
    const float* bv = bqkv + 2 * D + h * HD;

    __shared__ unsigned short As[128 * 32];
    __shared__ unsigned short Ws[64 * 32];
    const int t    = threadIdx.x;
    const int wave = t >> 6, lane = t & 63;

    floatx4 acc[2][4];
#pragma unroll
    for (int i = 0; i < 2; i++)
#pragma unroll
        for (int j = 0; j < 4; j++) acc[i][j] = (floatx4)0.f;

    const int lrow = lane >> 2;
    const int lcol = (lane & 3) * 8;
    const unsigned short* Ag = A  + (size_t)(wave * 32 + lrow) * D + lcol;
    const unsigned short* Wg = Wv + (size_t)(wave * 32 + lrow) * D + lcol;  // waves 0,1 only
    unsigned short* Asw = &As[wave * 32 * 32];
    unsigned short* Wsw = &Ws[wave * 32 * 32];
    const size_t rowskip = (size_t)16 * D;

    const int arow  = lane & 15;
    const int aquad = (lane >> 4) * 8;

    for (int k0 = 0; k0 < D; k0 += 32) {
        load_lds16(Ag + k0,           Asw);
        load_lds16(Ag + k0 + rowskip, Asw + 16 * 32);
        if (wave < 2) {
            load_lds16(Wg + k0,           Wsw);
            load_lds16(Wg + k0 + rowskip, Wsw + 16 * 32);
        }
        __syncthreads();

        bf16x8 af[2], wf[4];
#pragma unroll
        for (int mi = 0; mi < 2; mi++)
            af[mi] = *(const bf16x8*)&As[(wave * 32 + mi * 16 + arow) * 32 + aquad];
#pragma unroll
        for (int ni = 0; ni < 4; ni++)
            wf[ni] = *(const bf16x8*)&Ws[(ni * 16 + arow) * 32 + aquad];
#pragma unroll
        for (int mi = 0; mi < 2; mi++)
#pragma unroll
            for (int ni = 0; ni < 4; ni++)
                acc[mi][ni] = __builtin_amdgcn_mfma_f32_16x16x32_bf16(
                    af[mi], wf[ni], acc[mi][ni], 0, 0, 0);
        __syncthreads();
    }

    const int crow = (lane >> 4) * 4, ccol = lane & 15;
#pragma unroll
    for (int mi = 0; mi < 2; mi++) {
#pragma unroll
        for (int ni = 0; ni < 4; ni++) {
            const int e  = ni * 16 + ccol;
            const float bb = bv[e];
#pragma unroll
            for (int r = 0; r < 4; r++) {
                const int grow = mt * 128 + wave * 32 + mi * 16 + crow + r;
                float v = acc[mi][ni][r] + bb * Pmem[(size_t)grow * H + h]
                          + tok[(size_t)grow * D + h * HD + e];
                ctx[(size_t)grow * D + h * HD + e] = f32_to_bf16(v);
            }
        }
    }
}

// ---------------------------------------------------------------------------
extern "C" void kernel_launch(void* const* d_in, const int* in_sizes, int n_in,
                              void* d_out, int out_size, void* d_ws, size_t ws_size,
                              hipStream_t stream)
{
    const float* x    = (const float*)d_in[0];
    const float* pv   = (const float*)d_in[1];
    const float* Wqkv = (const float*)d_in[2];
    const float* bqkv = (const float*)d_in[3];
    const float* Wcol = (const float*)d_in[4];
    const float* bcol = (const float*)d_in[5];
    const float* Wout = (const float*)d_in[6];
    const float* bout = (const float*)d_in[7];
    float* out = (float*)d_out;

    char* p = (char*)d_ws;
    unsigned short* x_bf    = (unsigned short*)p; p += (size_t)2048 * 1024 * 2;
    unsigned short* W4_bf   = (unsigned short*)p; p += (size_t)4096 * 1024 * 2;   // Wqkv | Wcol
    unsigned short* Wout_bf = (unsigned short*)p; p += (size_t)1024 * 1024 * 2;
    float*          b4      = (float*)p;          p += (size_t)4096 * 4;
    unsigned short* ri_bf   = (unsigned short*)p; p += (size_t)16384 * 1024 * 2;
    unsigned short* qkv4_bf = (unsigned short*)p; p += (size_t)2048 * 4096 * 2;   // Q|K|V|Qcol
    unsigned short* WkT_bf  = (unsigned short*)p; p += (size_t)16 * 1024 * 64 * 2;
    unsigned short* VT_bf   = (unsigned short*)p; p += (size_t)16 * 64 * 2048 * 2; // V transposed per head
    float*          scores  = (float*)p;          p += (size_t)2048 * 16 * 8 * 4;
    float*          mwf     = (float*)p;          p += (size_t)2048 * 16 * 8 * 4;
    float*          Pmem    = (float*)p;          p += (size_t)2048 * 16 * 4;
    float*          tok     = (float*)p;          p += (size_t)2048 * 1024 * 4;
    unsigned short* ctx_bf  = (unsigned short*)p; p += (size_t)2048 * 1024 * 2;
    float*          Opart   = (float*)p;          p += (size_t)2048 * 64 * 64 * 4;
    float2*         mlpart  = (float2*)p;         p += (size_t)2048 * 64 * 8;
    // U and rbar have disjoint lifetimes (U dead after memsc) -> share buffer
    unsigned short* Urb     = (unsigned short*)p; p += (size_t)16 * 2048 * 1024 * 2;
    // ~182 MB total

    // LN -> ri (separate kernel for separable counters)
    prep_ln_kernel<<<LN_BLK, 256, 0, stream>>>(pv, ri_bf);
    // bf16 casts + bias concat
    prep_cvt_kernel<<<CVT_BLK + 4, 256, 0, stream>>>(x, Wqkv, Wcol, Wout, bqkv, bcol,
                                                     x_bf, W4_bf, Wout_bf, b4);
    // per-head transposed Wk for the U GEMM
    wkt_kernel<<<256, 256, 0, stream>>>(Wqkv, WkT_bf);
    // qkv4 = x @ [Wqkv|Wcol]^T + [bqkv|bcol]   (fused, N=4096; 64-row tiles)
    gemm_bf16_kernel<unsigned short, true, 64><<<dim3(32, 32, 1), 256, 0, stream>>>(
        x_bf, W4_bf, b4, qkv4_bf, 1024, 4096, 1024, 1024, 4096, 0, 0, 0);
    // global V transpose: VT[h][e][key]
    vtr_kernel<<<128, 256, 0, stream>>>(qkv4_bf, VT_bf);
    // U = Qcol @ Wk, written s-major: U[s][h][d] via ldc=H*D, zsC=D
    gemm_bf16_kernel<unsigned short, false, 128><<<dim3(8, 16, 16), 256, 0, stream>>>(
        qkv4_bf + 3 * D, WkT_bf, nullptr, Urb, 64, 1024, 4096, 64, H * D,
        (size_t)HD, (size_t)D * HD, (size_t)D);
    // mem_scores = (U . ri + qcol.bk) * scale   (MFMA, zero-staging)
    memsc_kernel<<<2048, 256, 0, stream>>>(Urb, ri_bf, qkv4_bf, bqkv, scores);
    // attention split (swapped-QK, dbuf, 1 barrier/tile, 4-way, LPT) + merge
    attn_split_kernel<<<2048, 256, 0, stream>>>(qkv4_bf, VT_bf, Opart, mlpart);
    attn_merge_kernel<<<512, 256, 0, stream>>>(Opart, mlpart, scores, tok, mwf, Pmem);
    // rbar = sum_l mwf * ri   (zero-staging; reuses U's buffer)
    rbar_kernel<<<2048, 256, 0, stream>>>(mwf, ri_bf, Urb);
    // ctx = tok + Wv[h] @ rbar[h] + bv*Pmem
    gemm_ctx_kernel<<<dim3(16, 16), 256, 0, stream>>>(Urb, W4_bf, bqkv, Pmem, tok, ctx_bf);
    // out = ctx @ Wout^T + bout   (64-row tiles -> 256 blocks)
    gemm_bf16_kernel<float, true, 64><<<dim3(8, 32, 1), 256, 0, stream>>>(
        ctx_bf, Wout_bf, bout, out, 1024, 1024, 1024, 1024, 1024, 0, 0, 0);
}